// Round 8
// baseline (179.026 us; speedup 1.0000x reference)
//
#include <hip/hip_runtime.h>
#include <stdint.h>

#define B_DIM 8192
#define H_DIM 1024
#define E_DIM 300
#define A_DIM 512
#define KP    1856   // 1024 + 320(pad of 300) + 512, = 29*64
#define KE0   1024   // start of embedding segment
#define KA0   1344   // start of context segment
#define BM    128
#define BK    64
#define NT    29     // KP/BK

typedef __bf16 bf16;
typedef bf16  bf16x8 __attribute__((ext_vector_type(8)));
typedef float f32x4  __attribute__((ext_vector_type(4)));

__device__ __forceinline__ uint16_t f2bf(float f) {
  uint32_t u = __float_as_uint(f);
  u += 0x7fff + ((u >> 16) & 1);   // round-to-nearest-even
  return (uint16_t)(u >> 16);
}

// ---- merged pack (one launch): X = [B][KP] bf16 [h|emb|pad|ctx],
//      W = [4096][KP] bf16 [Wh|Wx|pad|Wa] (row r = g*1024+o) ----
__global__ void pack_xw_kernel(const float* __restrict__ h,
                               const float* __restrict__ e,
                               const float* __restrict__ a,
                               const float* __restrict__ Wh,
                               const float* __restrict__ Wx,
                               const float* __restrict__ Wa,
                               uint16_t* __restrict__ X,
                               uint16_t* __restrict__ Wp) {
  int idx = blockIdx.x * blockDim.x + threadIdx.x;
  const int gpr  = KP / 8;                 // 232 groups per row
  const int xtot = B_DIM * gpr;
  __align__(16) uint16_t v[8];
  if (idx < xtot) {
    int row  = idx / gpr;
    int col0 = (idx % gpr) * 8;
#pragma unroll
    for (int j = 0; j < 8; ++j) {
      int c = col0 + j;
      float x;
      if (c < KE0) x = h[(size_t)row * H_DIM + c];
      else if (c < KA0) {
        int ce = c - KE0;
        x = (ce < E_DIM) ? e[(size_t)row * E_DIM + ce] : 0.f;
      } else x = a[(size_t)row * A_DIM + (c - KA0)];
      v[j] = f2bf(x);
    }
    *(uint4*)(X + (size_t)row * KP + col0) = *(const uint4*)v;
  } else {
    idx -= xtot;
    if (idx >= 4096 * gpr) return;
    int row  = idx / gpr;
    int col0 = (idx % gpr) * 8;
#pragma unroll
    for (int j = 0; j < 8; ++j) {
      int c = col0 + j;
      float x;
      if (c < KE0) x = Wh[(size_t)row * 1024 + c];
      else if (c < KA0) {
        int ce = c - KE0;
        x = (ce < E_DIM) ? Wx[(size_t)row * E_DIM + ce] : 0.f;
      } else x = Wa[(size_t)row * A_DIM + (c - KA0)];
      v[j] = f2bf(x);
    }
    *(uint4*)(Wp + (size_t)row * KP + col0) = *(const uint4*)v;
  }
}

__device__ __forceinline__ void async_copy16(const void* g, void* l) {
  __builtin_amdgcn_global_load_lds(
      (__attribute__((address_space(1))) void*)g,
      (__attribute__((address_space(3))) void*)l, 16, 0, 0);
}

__device__ __forceinline__ float fast_tanh(float x) {
  float ax = fabsf(x);
  float e  = __expf(2.f * ax);
  float r  = 1.f - 2.f / (e + 1.f);   // large ax: e->inf -> r->1 (graceful)
  return copysignf(r, x);
}

// ---- fused GEMM + gates: block = 128 rows x (32 units x 4 gates) ----
// r7-proven 2-barrier K-loop (multi-block overlap per m114), natural block
// order (L3-friendly), 2-way-free epilogue, tile-0 stage hoisted above
// bias init so its flight hides the bias-load latency.
__global__ __launch_bounds__(256, 4) void lstm_fused_kernel(
    const uint16_t* __restrict__ X, const uint16_t* __restrict__ W,
    const float* __restrict__ c_prev,
    const float* __restrict__ b0, const float* __restrict__ b1,
    const float* __restrict__ b2, const float* __restrict__ b3,
    float* __restrict__ out) {
  __shared__ __align__(16) uint16_t smem[2 * BM * BK];  // 32 KB
  uint16_t* As = smem;                 // [128][64] swizzled
  uint16_t* Bs = smem + BM * BK;       // [128][64] swizzled
  float*    pre = (float*)smem;        // epilogue reuse: [64][128]

  const int t    = threadIdx.x;
  const int lane = t & 63;
  const int wid  = t >> 6;
  const int wr   = wid >> 1, wc = wid & 1;
  const int m0   = blockIdx.x * BM;
  const int u0   = blockIdx.y * 32;
  const int lr   = lane & 15;   // fragment row/col
  const int kh   = lane >> 4;   // k-slot 0..3

  const int sr   = t >> 3;                         // staging row 0..31 per issue
  const int c8d  = (t & 7) * 8;                    // LDS dest chunk (linear)
  const int csrc = ((t & 7) ^ (sr & 7)) * 8;       // pre-swizzled global chunk

  // issue tile-0 staging FIRST: its ~500cyc flight hides the bias loads below
#pragma unroll
  for (int q = 0; q < 4; ++q) {
    async_copy16(X + (size_t)(m0 + q * 32 + sr) * KP + csrc,
                 As + (q * 32 + sr) * BK + c8d);
    async_copy16(W + (size_t)(q * 1024 + u0 + sr) * KP + csrc,
                 Bs + (q * 32 + sr) * BK + c8d);
  }

  f32x4 acc[4][4];
#pragma unroll
  for (int n = 0; n < 4; ++n) {
    int cl   = wc * 64 + n * 16 + lr;          // tile col 0..127
    int bidx = (cl >> 5) * H_DIM + u0 + (cl & 31);
    float bs = b0[bidx] + b1[bidx] + b2[bidx] + b3[bidx];
#pragma unroll
    for (int m = 0; m < 4; ++m) acc[m][n] = (f32x4){bs, bs, bs, bs};
  }

  for (int kt = 0; kt < NT; ++kt) {
    asm volatile("s_waitcnt vmcnt(0)" ::: "memory");
    __syncthreads();
#pragma unroll
    for (int kk = 0; kk < 2; ++kk) {
      bf16x8 af[4], bfr[4];
#pragma unroll
      for (int m = 0; m < 4; ++m) {
        int row = wr * 64 + m * 16 + lr;
        af[m] = *(const bf16x8*)(As + row * BK + (((kk * 4 + kh) ^ (row & 7)) * 8));
      }
#pragma unroll
      for (int n = 0; n < 4; ++n) {
        int row = wc * 64 + n * 16 + lr;
        bfr[n] = *(const bf16x8*)(Bs + row * BK + (((kk * 4 + kh) ^ (row & 7)) * 8));
      }
#pragma unroll
      for (int m = 0; m < 4; ++m)
#pragma unroll
        for (int n = 0; n < 4; ++n)
          acc[m][n] = __builtin_amdgcn_mfma_f32_16x16x32_bf16(af[m], bfr[n], acc[m][n], 0, 0, 0);
    }
    __syncthreads();
    if (kt + 1 < NT) {
      const int k0 = (kt + 1) * BK;
#pragma unroll
      for (int q = 0; q < 4; ++q) {
        async_copy16(X + (size_t)(m0 + q * 32 + sr) * KP + k0 + csrc,
                     As + (q * 32 + sr) * BK + c8d);
        async_copy16(W + (size_t)(q * 1024 + u0 + sr) * KP + k0 + csrc,
                     Bs + (q * 32 + sr) * BK + c8d);
      }
    }
  }

  // ---- fused epilogue: two 64-row phases through 32 KB LDS.
  //      pre[] col ROTATION swizzle: logical col c of row r stored at
  //      phys = (c&96) | (((c&31) + 8*((r>>2)&3)) & 31).
  //      Stores and loads both 2-way (free). The residual 2^20 in
  //      SQ_LDS_BANK_CONFLICT = 512 load-insts/block x 2048 blocks of
  //      benign 2-way aliasing (counter counts it, time does not).
  //      c_prev batched ahead of the dependent math chain. ----
  float* outh = out;
  float* outc = out + (size_t)B_DIM * H_DIM;
  const int eu = t & 31;
  const int rb = (t >> 5) * 8;
#pragma unroll 1
  for (int phase = 0; phase < 2; ++phase) {
    if (wr == phase) {
#pragma unroll
      for (int m = 0; m < 4; ++m)
#pragma unroll
        for (int n = 0; n < 4; ++n) {
          int col  = wc * 64 + n * 16 + lr;
          int colw = (col & 96) | (((col & 31) + 8 * kh) & 31);
#pragma unroll
          for (int j = 0; j < 4; ++j)
            pre[(m * 16 + kh * 4 + j) * 128 + colw] = acc[m][n][j];
        }
    }
    __syncthreads();
    size_t ob = (size_t)(m0 + phase * 64 + rb) * H_DIM + u0 + eu;
    float cp[8];
#pragma unroll
    for (int q = 0; q < 8; ++q) cp[q] = c_prev[ob + (size_t)q * H_DIM];
#pragma unroll
    for (int q = 0; q < 8; ++q) {
      int r  = rb + q;
      int rk = (r >> 2) & 3;
      int e0 = (eu + 8 * rk) & 31;     // phys within 32-group (goff adds 0 mod 32)
      float pi = pre[r * 128 +      e0];
      float pf = pre[r * 128 + 32 + e0];
      float po = pre[r * 128 + 64 + e0];
      float pg = pre[r * 128 + 96 + e0];
      float iv = 1.f / (1.f + __expf(-pi));
      float fv = 1.f / (1.f + __expf(-pf));
      float ov = 1.f / (1.f + __expf(-po));
      float gv = fast_tanh(pg);
      float ct = fv * cp[q] + iv * gv;
      float ht = ov * fast_tanh(ct);
      size_t o = ob + (size_t)q * H_DIM;
      outh[o] = ht;
      outc[o] = ct;
    }
    __syncthreads();
  }
}

extern "C" void kernel_launch(void* const* d_in, const int* in_sizes, int n_in,
                              void* d_out, int out_size, void* d_ws, size_t ws_size,
                              hipStream_t stream) {
  const float* h_prev = (const float*)d_in[0];
  const float* c_prev = (const float*)d_in[1];
  const float* emb    = (const float*)d_in[2];
  const float* ctx    = (const float*)d_in[3];
  const float* Wh     = (const float*)d_in[4];
  const float* Wx     = (const float*)d_in[5];
  const float* Wa     = (const float*)d_in[6];
  const float* bl     = (const float*)d_in[7];
  const float* bl2    = (const float*)d_in[8];
  const float* bl3    = (const float*)d_in[9];
  const float* bp     = (const float*)d_in[10];

  uint16_t* X = (uint16_t*)d_ws;                                   // 30.4 MB
  uint16_t* W = (uint16_t*)((char*)d_ws + (size_t)B_DIM * KP * 2); // 15.2 MB
  float* out = (float*)d_out;

  {
    int total = (B_DIM + 4096) * (KP / 8);
    pack_xw_kernel<<<(total + 255) / 256, 256, 0, stream>>>(h_prev, emb, ctx,
                                                            Wh, Wx, Wa, X, W);
  }
  dim3 grid(B_DIM / BM, H_DIM / 32);
  lstm_fused_kernel<<<grid, 256, 0, stream>>>(X, W, c_prev, bl, bl2, bl3, bp, out);
}

// Round 9
// 149.220 us; speedup vs baseline: 1.1997x; 1.1997x over previous
//
#include <hip/hip_runtime.h>
#include <stdint.h>

#define B_DIM 8192
#define H_DIM 1024
#define E_DIM 300
#define A_DIM 512
#define KP    1856   // 1024 + 320(pad of 300) + 512, = 29*64
#define KE0   1024   // start of embedding segment
#define KA0   1344   // start of context segment
#define BM    128
#define BK    64
#define NT    29     // KP/BK

typedef __bf16 bf16;
typedef bf16  bf16x8 __attribute__((ext_vector_type(8)));
typedef float f32x4  __attribute__((ext_vector_type(4)));

__device__ __forceinline__ uint16_t f2bf(float f) {
  uint32_t u = __float_as_uint(f);
  u += 0x7fff + ((u >> 16) & 1);   // round-to-nearest-even
  return (uint16_t)(u >> 16);
}

__device__ __forceinline__ void cvt8_store(const float4 x0, const float4 x1,
                                           uint16_t* dst) {
  __align__(16) uint16_t v[8];
  v[0] = f2bf(x0.x); v[1] = f2bf(x0.y); v[2] = f2bf(x0.z); v[3] = f2bf(x0.w);
  v[4] = f2bf(x1.x); v[5] = f2bf(x1.y); v[6] = f2bf(x1.z); v[7] = f2bf(x1.w);
  *(uint4*)dst = *(const uint4*)v;
}

// ---- pack X = [B][KP] bf16 : [h | emb | pad | ctx] ----
// Group-specialized: all segment boundaries except e/pad land on 8-elem
// group boundaries -> pure groups take branchless float4x2 vector loads
// (all row strides 16B-aligned); only group 165 (e[296..299]|pad) and the
// two all-pad groups (166,167) take the elementwise path.
__global__ void pack_x_kernel(const float* __restrict__ h,
                              const float* __restrict__ e,
                              const float* __restrict__ a,
                              uint16_t* __restrict__ X) {
  int idx = blockIdx.x * blockDim.x + threadIdx.x;
  const int gpr = KP / 8;                 // 232 groups per row
  if (idx >= B_DIM * gpr) return;
  int row  = idx / gpr;
  int g    = idx - row * gpr;
  int col0 = g * 8;
  uint16_t* dst = X + (size_t)row * KP + col0;
  if (col0 < KE0) {                       // pure h
    const float4* p = (const float4*)(h + (size_t)row * H_DIM + col0);
    cvt8_store(p[0], p[1], dst);
  } else if (col0 >= KA0) {               // pure ctx
    const float4* p = (const float4*)(a + (size_t)row * A_DIM + (col0 - KA0));
    cvt8_store(p[0], p[1], dst);
  } else if (col0 + 8 <= KE0 + E_DIM) {   // pure e (ce+8 <= 300)
    const float4* p = (const float4*)(e + (size_t)row * E_DIM + (col0 - KE0));
    cvt8_store(p[0], p[1], dst);
  } else {                                // e/pad boundary or all-pad
    __align__(16) uint16_t v[8];
    int ce = col0 - KE0;
#pragma unroll
    for (int j = 0; j < 8; ++j)
      v[j] = (ce + j < E_DIM) ? f2bf(e[(size_t)row * E_DIM + ce + j]) : (uint16_t)0;
    *(uint4*)dst = *(const uint4*)v;
  }
}

// ---- pack W = [4096][KP] bf16, row r = g*1024+o : [Wh | Wx | pad | Wa] ----
__global__ void pack_w_kernel(const float* __restrict__ Wh,
                              const float* __restrict__ Wx,
                              const float* __restrict__ Wa,
                              uint16_t* __restrict__ W) {
  int idx = blockIdx.x * blockDim.x + threadIdx.x;
  const int gpr = KP / 8;
  if (idx >= 4096 * gpr) return;
  int row  = idx / gpr;
  int g    = idx - row * gpr;
  int col0 = g * 8;
  uint16_t* dst = W + (size_t)row * KP + col0;
  if (col0 < KE0) {                       // pure Wh
    const float4* p = (const float4*)(Wh + (size_t)row * 1024 + col0);
    cvt8_store(p[0], p[1], dst);
  } else if (col0 >= KA0) {               // pure Wa
    const float4* p = (const float4*)(Wa + (size_t)row * A_DIM + (col0 - KA0));
    cvt8_store(p[0], p[1], dst);
  } else if (col0 + 8 <= KE0 + E_DIM) {   // pure Wx
    const float4* p = (const float4*)(Wx + (size_t)row * E_DIM + (col0 - KE0));
    cvt8_store(p[0], p[1], dst);
  } else {
    __align__(16) uint16_t v[8];
    int ce = col0 - KE0;
#pragma unroll
    for (int j = 0; j < 8; ++j)
      v[j] = (ce + j < E_DIM) ? f2bf(Wx[(size_t)row * E_DIM + ce + j]) : (uint16_t)0;
    *(uint4*)dst = *(const uint4*)v;
  }
}

__device__ __forceinline__ void async_copy16(const void* g, void* l) {
  __builtin_amdgcn_global_load_lds(
      (__attribute__((address_space(1))) void*)g,
      (__attribute__((address_space(3))) void*)l, 16, 0, 0);
}

__device__ __forceinline__ float fast_tanh(float x) {
  float ax = fabsf(x);
  float e  = __expf(2.f * ax);
  float r  = 1.f - 2.f / (e + 1.f);   // large ax: e->inf -> r->1 (graceful)
  return copysignf(r, x);
}

// ---- fused GEMM + gates: block = 128 rows x (32 units x 4 gates) ----
// r7-proven (133 us / 937 TF): 2-barrier K-loop with stage-at-top (multi-block
// overlap per m114), natural block order (L3-friendly), rotation-swizzled
// 2-way-free epilogue, batched c_prev, fast_tanh. BYTE-IDENTICAL to r7.
__global__ __launch_bounds__(256, 4) void lstm_fused_kernel(
    const uint16_t* __restrict__ X, const uint16_t* __restrict__ W,
    const float* __restrict__ c_prev,
    const float* __restrict__ b0, const float* __restrict__ b1,
    const float* __restrict__ b2, const float* __restrict__ b3,
    float* __restrict__ out) {
  __shared__ __align__(16) uint16_t smem[2 * BM * BK];  // 32 KB
  uint16_t* As = smem;                 // [128][64] swizzled
  uint16_t* Bs = smem + BM * BK;       // [128][64] swizzled
  float*    pre = (float*)smem;        // epilogue reuse: [64][128]

  const int t    = threadIdx.x;
  const int lane = t & 63;
  const int wid  = t >> 6;
  const int wr   = wid >> 1, wc = wid & 1;
  const int m0   = blockIdx.x * BM;
  const int u0   = blockIdx.y * 32;
  const int lr   = lane & 15;   // fragment row/col
  const int kh   = lane >> 4;   // k-slot 0..3

  f32x4 acc[4][4];
#pragma unroll
  for (int n = 0; n < 4; ++n) {
    int cl   = wc * 64 + n * 16 + lr;          // tile col 0..127
    int bidx = (cl >> 5) * H_DIM + u0 + (cl & 31);
    float bs = b0[bidx] + b1[bidx] + b2[bidx] + b3[bidx];
#pragma unroll
    for (int m = 0; m < 4; ++m) acc[m][n] = (f32x4){bs, bs, bs, bs};
  }

  const int sr   = t >> 3;                         // staging row 0..31 per issue
  const int c8d  = (t & 7) * 8;                    // LDS dest chunk (linear)
  const int csrc = ((t & 7) ^ (sr & 7)) * 8;       // pre-swizzled global chunk

  for (int kt = 0; kt < NT; ++kt) {
    const int k0 = kt * BK;
#pragma unroll
    for (int q = 0; q < 4; ++q) {
      async_copy16(X + (size_t)(m0 + q * 32 + sr) * KP + k0 + csrc,
                   As + (q * 32 + sr) * BK + c8d);
      // gate = q; B-row = gate*1024 + u0 + sr
      async_copy16(W + (size_t)(q * 1024 + u0 + sr) * KP + k0 + csrc,
                   Bs + (q * 32 + sr) * BK + c8d);
    }
    asm volatile("s_waitcnt vmcnt(0)" ::: "memory");
    __syncthreads();
#pragma unroll
    for (int kk = 0; kk < 2; ++kk) {
      bf16x8 af[4], bfr[4];
#pragma unroll
      for (int m = 0; m < 4; ++m) {
        int row = wr * 64 + m * 16 + lr;
        af[m] = *(const bf16x8*)(As + row * BK + (((kk * 4 + kh) ^ (row & 7)) * 8));
      }
#pragma unroll
      for (int n = 0; n < 4; ++n) {
        int row = wc * 64 + n * 16 + lr;
        bfr[n] = *(const bf16x8*)(Bs + row * BK + (((kk * 4 + kh) ^ (row & 7)) * 8));
      }
#pragma unroll
      for (int m = 0; m < 4; ++m)
#pragma unroll
        for (int n = 0; n < 4; ++n)
          acc[m][n] = __builtin_amdgcn_mfma_f32_16x16x32_bf16(af[m], bfr[n], acc[m][n], 0, 0, 0);
    }
    __syncthreads();
  }

  // ---- fused epilogue: two 64-row phases through 32 KB LDS.
  //      pre[] col ROTATION swizzle: logical col c of row r stored at
  //      phys = (c&96) | (((c&31) + 8*((r>>2)&3)) & 31).
  //      Stores and loads both 2-way (free). Residual 2^20 in
  //      SQ_LDS_BANK_CONFLICT = benign 2-way aliasing (counted, costless).
  //      c_prev batched ahead of the dependent math chain. ----
  float* outh = out;
  float* outc = out + (size_t)B_DIM * H_DIM;
  const int eu = t & 31;
  const int rb = (t >> 5) * 8;
#pragma unroll 1
  for (int phase = 0; phase < 2; ++phase) {
    if (wr == phase) {
#pragma unroll
      for (int m = 0; m < 4; ++m)
#pragma unroll
        for (int n = 0; n < 4; ++n) {
          int col  = wc * 64 + n * 16 + lr;
          int colw = (col & 96) | (((col & 31) + 8 * kh) & 31);
#pragma unroll
          for (int j = 0; j < 4; ++j)
            pre[(m * 16 + kh * 4 + j) * 128 + colw] = acc[m][n][j];
        }
    }
    __syncthreads();
    size_t ob = (size_t)(m0 + phase * 64 + rb) * H_DIM + u0 + eu;
    float cp[8];
#pragma unroll
    for (int q = 0; q < 8; ++q) cp[q] = c_prev[ob + (size_t)q * H_DIM];
#pragma unroll
    for (int q = 0; q < 8; ++q) {
      int r  = rb + q;
      int rk = (r >> 2) & 3;
      int e0 = (eu + 8 * rk) & 31;     // phys within 32-group (goff adds 0 mod 32)
      float pi = pre[r * 128 +      e0];
      float pf = pre[r * 128 + 32 + e0];
      float po = pre[r * 128 + 64 + e0];
      float pg = pre[r * 128 + 96 + e0];
      float iv = 1.f / (1.f + __expf(-pi));
      float fv = 1.f / (1.f + __expf(-pf));
      float ov = 1.f / (1.f + __expf(-po));
      float gv = fast_tanh(pg);
      float ct = fv * cp[q] + iv * gv;
      float ht = ov * fast_tanh(ct);
      size_t o = ob + (size_t)q * H_DIM;
      outh[o] = ht;
      outc[o] = ct;
    }
    __syncthreads();
  }
}

extern "C" void kernel_launch(void* const* d_in, const int* in_sizes, int n_in,
                              void* d_out, int out_size, void* d_ws, size_t ws_size,
                              hipStream_t stream) {
  const float* h_prev = (const float*)d_in[0];
  const float* c_prev = (const float*)d_in[1];
  const float* emb    = (const float*)d_in[2];
  const float* ctx    = (const float*)d_in[3];
  const float* Wh     = (const float*)d_in[4];
  const float* Wx     = (const float*)d_in[5];
  const float* Wa     = (const float*)d_in[6];
  const float* bl     = (const float*)d_in[7];
  const float* bl2    = (const float*)d_in[8];
  const float* bl3    = (const float*)d_in[9];
  const float* bp     = (const float*)d_in[10];

  uint16_t* X = (uint16_t*)d_ws;                                   // 30.4 MB
  uint16_t* W = (uint16_t*)((char*)d_ws + (size_t)B_DIM * KP * 2); // 15.2 MB
  float* out = (float*)d_out;

  {
    int total = B_DIM * (KP / 8);
    pack_x_kernel<<<(total + 255) / 256, 256, 0, stream>>>(h_prev, emb, ctx, X);
  }
  {
    int total = 4096 * (KP / 8);
    pack_w_kernel<<<(total + 255) / 256, 256, 0, stream>>>(Wh, Wx, Wa, W);
  }
  dim3 grid(B_DIM / BM, H_DIM / 32);
  lstm_fused_kernel<<<grid, 256, 0, stream>>>(X, W, c_prev, bl, bl2, bl3, bp, out);
}

// Round 10
// 146.448 us; speedup vs baseline: 1.2225x; 1.0189x over previous
//
#include <hip/hip_runtime.h>
#include <stdint.h>

#define B_DIM 8192
#define H_DIM 1024
#define E_DIM 300
#define A_DIM 512
#define KP    1856   // 1024 + 320(pad of 300) + 512, = 29*64
#define KE0   1024   // start of embedding segment
#define KA0   1344   // start of context segment
#define BM    128
#define BK    64
#define NT    29     // KP/BK

typedef __bf16 bf16;
typedef bf16  bf16x8 __attribute__((ext_vector_type(8)));
typedef float f32x4  __attribute__((ext_vector_type(4)));

__device__ __forceinline__ uint16_t f2bf(float f) {
  uint32_t u = __float_as_uint(f);
  u += 0x7fff + ((u >> 16) & 1);   // round-to-nearest-even
  return (uint16_t)(u >> 16);
}

__device__ __forceinline__ void cvt8_store(const float4 x0, const float4 x1,
                                           uint16_t* dst) {
  __align__(16) uint16_t v[8];
  v[0] = f2bf(x0.x); v[1] = f2bf(x0.y); v[2] = f2bf(x0.z); v[3] = f2bf(x0.w);
  v[4] = f2bf(x1.x); v[5] = f2bf(x1.y); v[6] = f2bf(x1.z); v[7] = f2bf(x1.w);
  *(uint4*)dst = *(const uint4*)v;
}

// ---- merged pack (ONE launch): X = [B][KP] bf16 [h|emb|pad|ctx],
//      W = [4096][KP] bf16 [Wh|Wx|pad|Wa] (row r = g*1024+o).
// Group-specialized (r9-proven): all segment boundaries except e/pad land on
// 8-elem group boundaries -> pure groups take branchless float4x2 vector
// loads (all row strides 16B-aligned); only the e/pad boundary group and the
// two all-pad groups take the elementwise path. Merging removes one launch
// + inter-launch gap (packs serialize on the single stream otherwise). ----
__global__ void pack_xw_kernel(const float* __restrict__ h,
                               const float* __restrict__ e,
                               const float* __restrict__ a,
                               const float* __restrict__ Wh,
                               const float* __restrict__ Wx,
                               const float* __restrict__ Wa,
                               uint16_t* __restrict__ X,
                               uint16_t* __restrict__ Wp) {
  int idx = blockIdx.x * blockDim.x + threadIdx.x;
  const int gpr  = KP / 8;                 // 232 groups per row
  const int xtot = B_DIM * gpr;
  const float* s0;   // segment base pointers for this group's row
  const float* s1;
  const float* s2;
  uint16_t* dst;
  int g;
  if (idx < xtot) {
    int row = idx / gpr;
    g   = idx - row * gpr;
    dst = X + (size_t)row * KP + g * 8;
    s0  = h + (size_t)row * H_DIM;
    s1  = e + (size_t)row * E_DIM;
    s2  = a + (size_t)row * A_DIM;
  } else {
    idx -= xtot;
    if (idx >= 4096 * gpr) return;
    int row = idx / gpr;
    g   = idx - row * gpr;
    dst = Wp + (size_t)row * KP + g * 8;
    s0  = Wh + (size_t)row * 1024;
    s1  = Wx + (size_t)row * E_DIM;
    s2  = Wa + (size_t)row * A_DIM;
  }
  int col0 = g * 8;
  if (col0 < KE0) {                       // pure h / Wh
    const float4* p = (const float4*)(s0 + col0);
    cvt8_store(p[0], p[1], dst);
  } else if (col0 >= KA0) {               // pure ctx / Wa
    const float4* p = (const float4*)(s2 + (col0 - KA0));
    cvt8_store(p[0], p[1], dst);
  } else if (col0 + 8 <= KE0 + E_DIM) {   // pure e / Wx  (ce+8 <= 300)
    const float4* p = (const float4*)(s1 + (col0 - KE0));
    cvt8_store(p[0], p[1], dst);
  } else {                                // e/pad boundary or all-pad
    __align__(16) uint16_t v[8];
    int ce = col0 - KE0;
#pragma unroll
    for (int j = 0; j < 8; ++j)
      v[j] = (ce + j < E_DIM) ? f2bf(s1[ce + j]) : (uint16_t)0;
    *(uint4*)dst = *(const uint4*)v;
  }
}

__device__ __forceinline__ void async_copy16(const void* g, void* l) {
  __builtin_amdgcn_global_load_lds(
      (__attribute__((address_space(1))) void*)g,
      (__attribute__((address_space(3))) void*)l, 16, 0, 0);
}

__device__ __forceinline__ float fast_tanh(float x) {
  float ax = fabsf(x);
  float e  = __expf(2.f * ax);
  float r  = 1.f - 2.f / (e + 1.f);   // large ax: e->inf -> r->1 (graceful)
  return copysignf(r, x);
}

// ---- fused GEMM + gates: block = 128 rows x (32 units x 4 gates) ----
// r7-proven (133 us / 943 TF): 2-barrier K-loop (multi-block overlap per
// m114), natural block order (L3-friendly), rotation-swizzled 2-way-free
// epilogue, batched c_prev, fast_tanh. BYTE-IDENTICAL to r7/r9.
__global__ __launch_bounds__(256, 4) void lstm_fused_kernel(
    const uint16_t* __restrict__ X, const uint16_t* __restrict__ W,
    const float* __restrict__ c_prev,
    const float* __restrict__ b0, const float* __restrict__ b1,
    const float* __restrict__ b2, const float* __restrict__ b3,
    float* __restrict__ out) {
  __shared__ __align__(16) uint16_t smem[2 * BM * BK];  // 32 KB
  uint16_t* As = smem;                 // [128][64] swizzled
  uint16_t* Bs = smem + BM * BK;       // [128][64] swizzled
  float*    pre = (float*)smem;        // epilogue reuse: [64][128]

  const int t    = threadIdx.x;
  const int lane = t & 63;
  const int wid  = t >> 6;
  const int wr   = wid >> 1, wc = wid & 1;
  const int m0   = blockIdx.x * BM;
  const int u0   = blockIdx.y * 32;
  const int lr   = lane & 15;   // fragment row/col
  const int kh   = lane >> 4;   // k-slot 0..3

  f32x4 acc[4][4];
#pragma unroll
  for (int n = 0; n < 4; ++n) {
    int cl   = wc * 64 + n * 16 + lr;          // tile col 0..127
    int bidx = (cl >> 5) * H_DIM + u0 + (cl & 31);
    float bs = b0[bidx] + b1[bidx] + b2[bidx] + b3[bidx];
#pragma unroll
    for (int m = 0; m < 4; ++m) acc[m][n] = (f32x4){bs, bs, bs, bs};
  }

  const int sr   = t >> 3;                         // staging row 0..31 per issue
  const int c8d  = (t & 7) * 8;                    // LDS dest chunk (linear)
  const int csrc = ((t & 7) ^ (sr & 7)) * 8;       // pre-swizzled global chunk

  for (int kt = 0; kt < NT; ++kt) {
    const int k0 = kt * BK;
#pragma unroll
    for (int q = 0; q < 4; ++q) {
      async_copy16(X + (size_t)(m0 + q * 32 + sr) * KP + k0 + csrc,
                   As + (q * 32 + sr) * BK + c8d);
      // gate = q; B-row = gate*1024 + u0 + sr
      async_copy16(W + (size_t)(q * 1024 + u0 + sr) * KP + k0 + csrc,
                   Bs + (q * 32 + sr) * BK + c8d);
    }
    asm volatile("s_waitcnt vmcnt(0)" ::: "memory");
    __syncthreads();
#pragma unroll
    for (int kk = 0; kk < 2; ++kk) {
      bf16x8 af[4], bfr[4];
#pragma unroll
      for (int m = 0; m < 4; ++m) {
        int row = wr * 64 + m * 16 + lr;
        af[m] = *(const bf16x8*)(As + row * BK + (((kk * 4 + kh) ^ (row & 7)) * 8));
      }
#pragma unroll
      for (int n = 0; n < 4; ++n) {
        int row = wc * 64 + n * 16 + lr;
        bfr[n] = *(const bf16x8*)(Bs + row * BK + (((kk * 4 + kh) ^ (row & 7)) * 8));
      }
#pragma unroll
      for (int m = 0; m < 4; ++m)
#pragma unroll
        for (int n = 0; n < 4; ++n)
          acc[m][n] = __builtin_amdgcn_mfma_f32_16x16x32_bf16(af[m], bfr[n], acc[m][n], 0, 0, 0);
    }
    __syncthreads();
  }

  // ---- fused epilogue: two 64-row phases through 32 KB LDS.
  //      pre[] col ROTATION swizzle: logical col c of row r stored at
  //      phys = (c&96) | (((c&31) + 8*((r>>2)&3)) & 31).
  //      Stores and loads both 2-way (free). Residual 2^20 in
  //      SQ_LDS_BANK_CONFLICT = benign 2-way aliasing (counted, costless).
  //      c_prev batched ahead of the dependent math chain. ----
  float* outh = out;
  float* outc = out + (size_t)B_DIM * H_DIM;
  const int eu = t & 31;
  const int rb = (t >> 5) * 8;
#pragma unroll 1
  for (int phase = 0; phase < 2; ++phase) {
    if (wr == phase) {
#pragma unroll
      for (int m = 0; m < 4; ++m)
#pragma unroll
        for (int n = 0; n < 4; ++n) {
          int col  = wc * 64 + n * 16 + lr;
          int colw = (col & 96) | (((col & 31) + 8 * kh) & 31);
#pragma unroll
          for (int j = 0; j < 4; ++j)
            pre[(m * 16 + kh * 4 + j) * 128 + colw] = acc[m][n][j];
        }
    }
    __syncthreads();
    size_t ob = (size_t)(m0 + phase * 64 + rb) * H_DIM + u0 + eu;
    float cp[8];
#pragma unroll
    for (int q = 0; q < 8; ++q) cp[q] = c_prev[ob + (size_t)q * H_DIM];
#pragma unroll
    for (int q = 0; q < 8; ++q) {
      int r  = rb + q;
      int rk = (r >> 2) & 3;
      int e0 = (eu + 8 * rk) & 31;     // phys within 32-group (goff adds 0 mod 32)
      float pi = pre[r * 128 +      e0];
      float pf = pre[r * 128 + 32 + e0];
      float po = pre[r * 128 + 64 + e0];
      float pg = pre[r * 128 + 96 + e0];
      float iv = 1.f / (1.f + __expf(-pi));
      float fv = 1.f / (1.f + __expf(-pf));
      float ov = 1.f / (1.f + __expf(-po));
      float gv = fast_tanh(pg);
      float ct = fv * cp[q] + iv * gv;
      float ht = ov * fast_tanh(ct);
      size_t o = ob + (size_t)q * H_DIM;
      outh[o] = ht;
      outc[o] = ct;
    }
    __syncthreads();
  }
}

extern "C" void kernel_launch(void* const* d_in, const int* in_sizes, int n_in,
                              void* d_out, int out_size, void* d_ws, size_t ws_size,
                              hipStream_t stream) {
  const float* h_prev = (const float*)d_in[0];
  const float* c_prev = (const float*)d_in[1];
  const float* emb    = (const float*)d_in[2];
  const float* ctx    = (const float*)d_in[3];
  const float* Wh     = (const float*)d_in[4];
  const float* Wx     = (const float*)d_in[5];
  const float* Wa     = (const float*)d_in[6];
  const float* bl     = (const float*)d_in[7];
  const float* bl2    = (const float*)d_in[8];
  const float* bl3    = (const float*)d_in[9];
  const float* bp     = (const float*)d_in[10];

  uint16_t* X = (uint16_t*)d_ws;                                   // 30.4 MB
  uint16_t* W = (uint16_t*)((char*)d_ws + (size_t)B_DIM * KP * 2); // 15.2 MB
  float* out = (float*)d_out;

  {
    int total = (B_DIM + 4096) * (KP / 8);
    pack_xw_kernel<<<(total + 255) / 256, 256, 0, stream>>>(h_prev, emb, ctx,
                                                            Wh, Wx, Wa, X, W);
  }
  dim3 grid(B_DIM / BM, H_DIM / 32);
  lstm_fused_kernel<<<grid, 256, 0, stream>>>(X, W, c_prev, bl, bl2, bl3, bp, out);
}